// Round 13
// baseline (960.661 us; speedup 1.0000x reference)
//
#include <hip/hip_runtime.h>
#include <hip/hip_bf16.h>
#include <cstdint>
#include <cstddef>

#define BB   16
#define NN   8192
#define DD   64
#define MM   256
#define SS   32
#define OUTC 128
#define WCC  64

using short8 = __attribute__((ext_vector_type(8))) short;
using f32x4  = __attribute__((ext_vector_type(4))) float;

__device__ __forceinline__ float bnf(float x, float g, float be){
    const float BNS = 0.99999500003749969f; // 1/sqrt(1+1e-5)
    return g * (x * BNS) + be;
}
__device__ __forceinline__ unsigned short f2bf(float f){
    __hip_bfloat16 h = __float2bfloat16(f);
    return *reinterpret_cast<unsigned short*>(&h);
}
__device__ __forceinline__ float bf2f(unsigned short u){
    return __uint_as_float(((unsigned)u) << 16);
}

// ---------------- zero the sync flags (d_ws not re-poisoned between replays) ----------------
__global__ __launch_bounds__(64) void k_zero(int* __restrict__ syncw){
  if (threadIdx.x < 32) syncw[threadIdx.x] = 0;
}

// ============ fused prologue: FPS (blocks 0-15) ∥ transposes+casts then chunk-gated group ============
// grid = 256 blocks (=CU count), 100KB LDS -> 1 block/CU -> all co-resident -> spin is deadlock-free.
__global__ __launch_bounds__(256, 1) void k_pre(const float* __restrict__ xyz, float* __restrict__ nxyz,
    const float* __restrict__ feature, unsigned short* __restrict__ featB,
    const float* __restrict__ wl, unsigned short* __restrict__ wlB,
    const float* __restrict__ wf, unsigned short* __restrict__ wfB,
    const float* __restrict__ w0, const float* __restrict__ b0,
    const float* __restrict__ g0, const float* __restrict__ be0,
    const float* __restrict__ w1, const float* __restrict__ b1,
    const float* __restrict__ g1, const float* __restrict__ be1,
    const float* __restrict__ w2, const float* __restrict__ b2,
    unsigned short* __restrict__ aggB,
    int* __restrict__ flags /*16*/, int* __restrict__ tdone /*16*/){
  __shared__ union {
    struct {
      float sxyz[NN*3];
      float snew[MM*3];
      unsigned long long skey[2][4];
    } f;
    float tile[64][65];
    struct {
      int   wlist[4][SS];
      int   wcnt[4];
      int   sidx[SS];
      float sgx[3][SS];
      float sh0[SS][WCC];
      float sh1[SS][WCC];
      float swt[SS][WCC];
    } g;
  } sm;
  const int t = threadIdx.x;
  const int blk = blockIdx.x;

  if (blk < 16){
    // ---- FPS: 256 thr, expansion distance, u64 DPP chain, 1 barrier/step, chunked publish ----
    const int b = blk;
    const float* xb = xyz + (size_t)b*NN*3;
    for (int i = t; i < NN*3; i += 256) sm.f.sxyz[i] = xb[i];
    float px[32], py[32], pz[32], pn[32], dist[32];
#pragma unroll
    for (int i=0;i<32;i++){
      const int id = i*256 + t;
      px[i] = xb[id*3+0]; py[i] = xb[id*3+1]; pz[i] = xb[id*3+2];
      pn[i] = px[i]*px[i] + py[i]*py[i] + pz[i]*pz[i];
      dist[i] = 1e10f;
    }
    __syncthreads();
    float lx = sm.f.sxyz[0], ly = sm.f.sxyz[1], lz = sm.f.sxyz[2];
    if (t==0){ sm.f.snew[0]=lx; sm.f.snew[1]=ly; sm.f.snew[2]=lz; }
    for (int step=1; step<MM; ++step){
      const float nlx = -2.0f*lx, nly = -2.0f*ly, nlz = -2.0f*lz;
      const float l2s = lx*lx + ly*ly + lz*lz;
      float bv = 0.0f; int bil = 0;
#pragma unroll
      for (int i=0;i<32;i++){
        float c  = pn[i] + l2s;
        float d  = __builtin_fmaf(px[i], nlx, __builtin_fmaf(py[i], nly, __builtin_fmaf(pz[i], nlz, c)));
        float nd = fminf(dist[i], d);
        dist[i] = nd;
        bool gt = nd > bv;
        bv  = gt ? nd : bv;
        bil = gt ? i  : bil;
      }
      const int bi = bil*256 + t;
      unsigned long long key = ((unsigned long long)__float_as_uint(bv) << 32) | (unsigned)(NN-1 - bi);
#define DPP_U64_MAX(CTRL) do { \
        unsigned lo_ = (unsigned)key, hi_ = (unsigned)(key >> 32); \
        unsigned olo_ = (unsigned)__builtin_amdgcn_update_dpp((int)lo_, (int)lo_, (CTRL), 0xF, 0xF, 0); \
        unsigned ohi_ = (unsigned)__builtin_amdgcn_update_dpp((int)hi_, (int)hi_, (CTRL), 0xF, 0xF, 0); \
        unsigned long long ok_ = ((unsigned long long)ohi_ << 32) | olo_; \
        key = ok_ > key ? ok_ : key; \
      } while(0)
      DPP_U64_MAX(0x111);
      DPP_U64_MAX(0x112);
      DPP_U64_MAX(0x114);
      DPP_U64_MAX(0x118);
      DPP_U64_MAX(0x142);
      DPP_U64_MAX(0x143);
#undef DPP_U64_MAX
      {
        unsigned klo = (unsigned)__builtin_amdgcn_readlane((int)(unsigned)key, 63);
        unsigned khi = (unsigned)__builtin_amdgcn_readlane((int)(unsigned)(key >> 32), 63);
        key = ((unsigned long long)khi << 32) | klo;
      }
      const int p = step & 1;
      if ((t & 63) == 0) sm.f.skey[p][t>>6] = key;
      __syncthreads();   // single barrier per step
      unsigned long long k0=sm.f.skey[p][0], k1=sm.f.skey[p][1], k2=sm.f.skey[p][2], k3=sm.f.skey[p][3];
      unsigned long long ka = k0>k1?k0:k1, kb = k2>k3?k2:k3;
      unsigned long long kw = ka>kb?ka:kb;
      const int bid = (NN-1) - (int)(unsigned)(kw & 0xFFFFFFFFull);
      lx = sm.f.sxyz[bid*3+0]; ly = sm.f.sxyz[bid*3+1]; lz = sm.f.sxyz[bid*3+2];
      if (t==0){ sm.f.snew[step*3+0]=lx; sm.f.snew[step*3+1]=ly; sm.f.snew[step*3+2]=lz; }
      // publish chunks 0,1,2 (m in [64c, 64c+64)) as they complete
      if ((step & 63) == 63 && step != MM-1){
        __syncthreads();
        const int chunk = step >> 6;
        for (int i=t; i<192; i+=256) nxyz[(size_t)b*768 + chunk*192 + i] = sm.f.snew[chunk*192 + i];
        __threadfence();
        __syncthreads();
        if (t==0) __hip_atomic_store(&flags[b], chunk+1, __ATOMIC_RELEASE, __HIP_MEMORY_SCOPE_AGENT);
      }
    }
    __syncthreads();
    for (int i=t; i<192; i+=256) nxyz[(size_t)b*768 + 576 + i] = sm.f.snew[576 + i];
    __threadfence();
    __syncthreads();
    if (t==0) __hip_atomic_store(&flags[b], 4, __ATOMIC_RELEASE, __HIP_MEMORY_SCOPE_AGENT);
    return;
  }

  // ================= worker blocks (16..255): transposes/casts, then group tasks =================
  const int wb = blk - 16;   // 0..239
  // ---- phase 1: 2048 transpose tiles + 512 wl-cast + 24 wf-cast tasks ----
  for (int task = wb; task < 2048+512+24; task += 240){
    if (task < 2048){
      const int b  = task >> 7;
      const int n0 = (task & 127) << 6;
      {
        const int d = t >> 2, j0 = (t & 3) << 4;
        const float* src = feature + ((size_t)b*DD + d)*NN + n0 + j0;
#pragma unroll
        for (int i=0;i<16;i+=4){
          float4 v = *(const float4*)(src + i);
          sm.tile[d][j0+i+0]=v.x; sm.tile[d][j0+i+1]=v.y; sm.tile[d][j0+i+2]=v.z; sm.tile[d][j0+i+3]=v.w;
        }
      }
      __syncthreads();
      {
        const int j = t >> 2, d0 = (t & 3) << 4;
        unsigned short hv[16];
#pragma unroll
        for (int i=0;i<16;i++) hv[i] = f2bf(sm.tile[d0+i][j]);
        unsigned short* dst = featB + ((size_t)b*NN + n0 + j)*64 + d0;
        *(uint4*)(dst)     = *(uint4*)(&hv[0]);
        *(uint4*)(dst + 8) = *(uint4*)(&hv[8]);
      }
      __threadfence();
      __syncthreads();
      if (t==0) __hip_atomic_fetch_add(&tdone[b], 1, __ATOMIC_RELEASE, __HIP_MEMORY_SCOPE_AGENT);
      __syncthreads();
    } else if (task < 2048+512){
      int idx = (task-2048)*1024 + t*4;
      float4 v = *(const float4*)(wl + idx);
      ushort4 h = make_ushort4(f2bf(v.x), f2bf(v.y), f2bf(v.z), f2bf(v.w));
      *(ushort4*)(wlB + idx) = h;
    } else {
      int idx = (task-2048-512)*1024 + t*4;
      if (idx < 128*192){
        float4 v = *(const float4*)(wf + idx);
        ushort4 h = make_ushort4(f2bf(v.x), f2bf(v.y), f2bf(v.z), f2bf(v.w));
        *(ushort4*)(wfB + idx) = h;
      }
    }
  }

  // ---- phase 2: group tasks, chunk-gated on FPS progress ----
  const int c  = t & 63;
  const int wg = t >> 6;
  const float w0r0 = w0[c*3+0], w0r1 = w0[c*3+1], w0r2 = w0[c*3+2];
  const float b0c=b0[c], g0c=g0[c], be0c=be0[c];
  const float b1c=b1[c], g1c=g1[c], be1c=be1[c], b2c=b2[c];
  float w1r[64], w2r[64];
#pragma unroll
  for (int i=0;i<16;i++){
    float4 v = *(const float4*)(w1 + c*64 + i*4);
    w1r[i*4+0]=v.x; w1r[i*4+1]=v.y; w1r[i*4+2]=v.z; w1r[i*4+3]=v.w;
    float4 u = *(const float4*)(w2 + c*64 + i*4);
    w2r[i*4+0]=u.x; w2r[i*4+1]=u.y; w2r[i*4+2]=u.z; w2r[i*4+3]=u.w;
  }
  const float R2 = (float)(0.4*0.4);

  for (int T = wb; T < 4096; T += 240){
    const int chunk = T >> 10;          // tasks ascend in chunk within each block
    const int i1k   = T & 1023;
    const int b     = i1k & 15;
    const int m     = chunk*64 + (i1k >> 4);
    const int bm    = b*256 + m;
    // wait for FPS chunk + featB tiles of batch b
    while (__hip_atomic_load(&flags[b], __ATOMIC_ACQUIRE, __HIP_MEMORY_SCOPE_AGENT) < chunk+1)
      __builtin_amdgcn_s_sleep(8);
    while (__hip_atomic_load(&tdone[b], __ATOMIC_ACQUIRE, __HIP_MEMORY_SCOPE_AGENT) < 128)
      __builtin_amdgcn_s_sleep(8);

    const float cx = nxyz[bm*3+0], cy = nxyz[bm*3+1], cz = nxyz[bm*3+2];
    const float* xb = xyz + (size_t)b*NN*3;
    // ---- ball query: each wave scans its quarter, collects first 32 in order ----
    {
      int cnt = 0;
      const int base = wg*2048;
      for (int n0=0; n0<2048 && cnt<SS; n0+=64){
        int n = base + n0 + c;
        float dx = xb[n*3+0]-cx, dy = xb[n*3+1]-cy, dz = xb[n*3+2]-cz;
        float d2 = dx*dx+dy*dy+dz*dz;
        bool in = (d2 <= R2);
        unsigned long long mk = __ballot(in);
        int rank = cnt + (int)__popcll(mk & ((1ull<<c)-1ull));
        if (in && rank < SS) sm.g.wlist[wg][rank] = n;
        cnt += (int)__popcll(mk);
      }
      if (c==0) sm.g.wcnt[wg] = min(cnt, SS);
    }
    __syncthreads();
    if (t < SS){
      const int c0=sm.g.wcnt[0], c1=sm.g.wcnt[1], c2=sm.g.wcnt[2], c3=sm.g.wcnt[3];
      const int a1=c0+c1, a2=a1+c2, a3=a2+c3;
      int idx;
      if      (t < c0) idx = sm.g.wlist[0][t];
      else if (t < a1) idx = sm.g.wlist[1][t-c0];
      else if (t < a2) idx = sm.g.wlist[2][t-a1];
      else if (t < a3) idx = sm.g.wlist[3][t-a2];
      else idx = (c0>0) ? sm.g.wlist[0][0] : (c1>0) ? sm.g.wlist[1][0] : (c2>0) ? sm.g.wlist[2][0] : sm.g.wlist[3][0];
      sm.g.sidx[t] = idx;
      sm.g.sgx[0][t] = xb[idx*3+0]-cx;
      sm.g.sgx[1][t] = xb[idx*3+1]-cy;
      sm.g.sgx[2][t] = xb[idx*3+2]-cz;
    }
    __syncthreads();
#pragma unroll
    for (int i=0;i<8;i++){
      const int s = i*4 + wg;
      float pre = w0r0*sm.g.sgx[0][s] + w0r1*sm.g.sgx[1][s] + w0r2*sm.g.sgx[2][s] + b0c;
      sm.g.sh0[s][c] = fmaxf(bnf(pre, g0c, be0c), 0.f);
    }
    __syncthreads();
#pragma unroll
    for (int i=0;i<8;i++){
      const int s = i*4 + wg;
      float a = b1c;
#pragma unroll
      for (int k=0;k<64;k+=4){
        float4 h = *(const float4*)(&sm.g.sh0[s][k]);
        a += w1r[k]*h.x + w1r[k+1]*h.y + w1r[k+2]*h.z + w1r[k+3]*h.w;
      }
      sm.g.sh1[s][c] = fmaxf(bnf(a, g1c, be1c), 0.f);
    }
    __syncthreads();
#pragma unroll
    for (int i=0;i<8;i++){
      const int s = i*4 + wg;
      float a = b2c;
#pragma unroll
      for (int k=0;k<64;k+=4){
        float4 h = *(const float4*)(&sm.g.sh1[s][k]);
        a += w2r[k]*h.x + w2r[k+1]*h.y + w2r[k+2]*h.z + w2r[k+3]*h.w;
      }
      sm.g.swt[s][c] = a;
    }
    __syncthreads();
    // ---- aggregation ----
    const int d = c;
    float acc[16];
#pragma unroll
    for (int j=0;j<16;j++) acc[j]=0.f;
    const unsigned short* fb = featB + (size_t)b*NN*64;
    for (int s=0;s<SS;s++){
      float fv = bf2f(fb[(size_t)sm.g.sidx[s]*64 + d]);
#pragma unroll
      for (int j=0;j<16;j++) acc[j] += fv * sm.g.swt[s][wg*16+j];
    }
    unsigned short h[16];
#pragma unroll
    for (int j=0;j<16;j++) h[j] = f2bf(acc[j]);
    unsigned short* ab = aggB + (size_t)bm*4096 + d*64 + wg*16;
    *(uint4*)(ab)     = *(uint4*)(&h[0]);
    *(uint4*)(ab + 8) = *(uint4*)(&h[8]);
    __syncthreads();
  }
}

// ---------------- new_feature GEMM via MFMA bf16, split-K x8 partials ----------------
__global__ __launch_bounds__(256) void k_nf_part(const unsigned short* __restrict__ aggB,
                                                 const unsigned short* __restrict__ wlB,
                                                 float* __restrict__ part){
  const int blk = blockIdx.x;
  const int rb  = blk >> 3;
  const int ks  = blk & 7;
  const int wid = threadIdx.x >> 6, lane = threadIdx.x & 63;
  const int m0 = rb*64 + wid*16;
  const int r  = lane & 15, kg = lane >> 4;
  f32x4 acc[8];
#pragma unroll
  for (int i=0;i<8;i++) acc[i] = (f32x4){0.f,0.f,0.f,0.f};
  const short* arow = (const short*)aggB + (size_t)(m0 + r)*4096 + ks*512 + kg*8;
  const short* brow = (const short*)wlB  + (size_t)r*4096        + ks*512 + kg*8;
#pragma unroll 4
  for (int kc=0; kc<16; kc++){
    short8 a = *(const short8*)(arow + kc*32);
#pragma unroll
    for (int ot=0; ot<8; ot++){
      short8 bfr = *(const short8*)(brow + (size_t)ot*16*4096 + kc*32);
      acc[ot] = __builtin_amdgcn_mfma_f32_16x16x32_bf16(a, bfr, acc[ot], 0, 0, 0);
    }
  }
  float* pb = part + ((size_t)ks << 19);
#pragma unroll
  for (int ot=0; ot<8; ot++){
#pragma unroll
    for (int rr=0; rr<4; rr++){
      int row = m0 + kg*4 + rr;
      pb[(size_t)row*128 + ot*16 + r] = acc[ot][rr];
    }
  }
}

// ---------------- nf epilogue: sum 8 partials + bias + bn + relu ----------------
__global__ __launch_bounds__(256) void k_nf_ep(const float* __restrict__ part,
    const float* __restrict__ bl, const float* __restrict__ gl, const float* __restrict__ bel,
    float* __restrict__ nfT){
  const int gid = blockIdx.x*256 + threadIdx.x;
  const int base = gid*4;
  const int o0 = base & 127;
  float sum[4] = {0.f, 0.f, 0.f, 0.f};
#pragma unroll
  for (int s=0;s<8;s++){
    float4 v = *(const float4*)(part + ((size_t)s<<19) + base);
    sum[0]+=v.x; sum[1]+=v.y; sum[2]+=v.z; sum[3]+=v.w;
  }
  float ov[4];
#pragma unroll
  for (int j=0;j<4;j++){
    const int o = o0 + j;
    ov[j] = fmaxf(bnf(sum[j] + bl[o], gl[o], bel[o]), 0.f);
  }
  *(float4*)(nfT + base) = make_float4(ov[0],ov[1],ov[2],ov[3]);
}

// ---------------- fused: 3-NN interp + final conv via MFMA bf16 ----------------
__global__ __launch_bounds__(256) void k_final(const float* __restrict__ xyz,
    const float* __restrict__ nxyz, const float* __restrict__ nfT,
    const unsigned short* __restrict__ featB, const unsigned short* __restrict__ wfB,
    const float* __restrict__ bf, const float* __restrict__ gf, const float* __restrict__ bef,
    float* __restrict__ out){
  const int blk = blockIdx.x;
  const int b  = blk >> 6;
  const int n0 = (blk & 63) << 7;
  __shared__ float snew[MM*3];
  __shared__ float sw[128][3];
  __shared__ int   si[128][3];
  const int t = threadIdx.x;
  if (t < 192){
    float4 v = *(const float4*)(nxyz + (size_t)b*MM*3 + t*4);
    snew[t*4+0]=v.x; snew[t*4+1]=v.y; snew[t*4+2]=v.z; snew[t*4+3]=v.w;
  }
  __syncthreads();
  if (t < 128){
    const int n = n0 + t;
    const float x = xyz[((size_t)b*NN+n)*3+0];
    const float y = xyz[((size_t)b*NN+n)*3+1];
    const float z = xyz[((size_t)b*NN+n)*3+2];
    float d1=1e30f, d2=1e30f, d3=1e30f; int i1=0,i2=0,i3=0;
    for (int m=0;m<MM;m++){
      float dx=x-snew[m*3+0], dy=y-snew[m*3+1], dz=z-snew[m*3+2];
      float d = dx*dx+dy*dy+dz*dz;
      if (d < d3){
        if (d < d1){ d3=d2;i3=i2; d2=d1;i2=i1; d1=d;i1=m; }
        else if (d < d2){ d3=d2;i3=i2; d2=d;i2=m; }
        else { d3=d;i3=m; }
      }
    }
    float r1=1.f/(d1+1e-8f), r2=1.f/(d2+1e-8f), r3=1.f/(d3+1e-8f);
    float rs = 1.f/(r1+r2+r3);
    sw[t][0]=r1*rs; sw[t][1]=r2*rs; sw[t][2]=r3*rs;
    si[t][0]=i1; si[t][1]=i2; si[t][2]=i3;
  }
  __syncthreads();

  const int w = t >> 6, lane = t & 63;
  const int r = lane & 15, kg = lane >> 4;
  float wA[8][3]; int iA[8][3];
#pragma unroll
  for (int nt=0;nt<8;nt++){
    int n = nt*16 + r;
    wA[nt][0]=sw[n][0]; wA[nt][1]=sw[n][1]; wA[nt][2]=sw[n][2];
    iA[nt][0]=si[n][0]*128; iA[nt][1]=si[n][1]*128; iA[nt][2]=si[n][2]*128;
  }
  const float* nfb = nfT + (size_t)b*MM*128;
  const unsigned short* fbB = featB + ((size_t)b*NN + n0)*64;
  const unsigned short* wfRow0 = wfB + (size_t)(w*32 +      r)*192 + kg*8;
  const unsigned short* wfRow1 = wfB + (size_t)(w*32 + 16 + r)*192 + kg*8;
  f32x4 acc[2][8];
#pragma unroll
  for (int i=0;i<2;i++)
#pragma unroll
    for (int j=0;j<8;j++) acc[i][j] = (f32x4){0.f,0.f,0.f,0.f};

#pragma unroll
  for (int c=0;c<6;c++){
    short8 a0 = *(const short8*)(wfRow0 + c*32);
    short8 a1 = *(const short8*)(wfRow1 + c*32);
    if (c < 4){
      const int k8 = c*32 + kg*8;
#pragma unroll
      for (int nt=0;nt<8;nt++){
        const float* p0 = nfb + iA[nt][0] + k8;
        const float* p1 = nfb + iA[nt][1] + k8;
        const float* p2 = nfb + iA[nt][2] + k8;
        float4 xa = *(const float4*)(p0), xb4 = *(const float4*)(p0+4);
        float4 ya = *(const float4*)(p1), yb4 = *(const float4*)(p1+4);
        float4 za = *(const float4*)(p2), zb4 = *(const float4*)(p2+4);
        const float w0v=wA[nt][0], w1v=wA[nt][1], w2v=wA[nt][2];
        float e0 = w0v*xa.x + w1v*ya.x + w2v*za.x;
        float e1 = w0v*xa.y + w1v*ya.y + w2v*za.y;
        float e2 = w0v*xa.z + w1v*ya.z + w2v*za.z;
        float e3 = w0v*xa.w + w1v*ya.w + w2v*za.w;
        float e4 = w0v*xb4.x + w1v*yb4.x + w2v*zb4.x;
        float e5 = w0v*xb4.y + w1v*yb4.y + w2v*zb4.y;
        float e6 = w0v*xb4.z + w1v*yb4.z + w2v*zb4.z;
        float e7 = w0v*xb4.w + w1v*yb4.w + w2v*zb4.w;
        short8 bfr = { (short)f2bf(e0), (short)f2bf(e1), (short)f2bf(e2), (short)f2bf(e3),
                       (short)f2bf(e4), (short)f2bf(e5), (short)f2bf(e6), (short)f2bf(e7) };
        acc[0][nt] = __builtin_amdgcn_mfma_f32_16x16x32_bf16(a0, bfr, acc[0][nt], 0, 0, 0);
        acc[1][nt] = __builtin_amdgcn_mfma_f32_16x16x32_bf16(a1, bfr, acc[1][nt], 0, 0, 0);
      }
    } else {
      const int d8 = (c-4)*32 + kg*8;
#pragma unroll
      for (int nt=0;nt<8;nt++){
        short8 bfr = *(const short8*)(fbB + (size_t)(nt*16 + r)*64 + d8);
        acc[0][nt] = __builtin_amdgcn_mfma_f32_16x16x32_bf16(a0, bfr, acc[0][nt], 0, 0, 0);
        acc[1][nt] = __builtin_amdgcn_mfma_f32_16x16x32_bf16(a1, bfr, acc[1][nt], 0, 0, 0);
      }
    }
  }
#pragma unroll
  for (int ot=0; ot<2; ot++){
#pragma unroll
    for (int rr=0; rr<4; rr++){
      const int o = w*32 + ot*16 + kg*4 + rr;
      const float bfo = bf[o], gfo = gf[o], befo = bef[o];
      float* dst = out + ((size_t)b*OUTC + o)*NN + n0 + r;
#pragma unroll
      for (int nt=0;nt<8;nt++){
        float val = fmaxf(bnf(acc[ot][nt][rr] + bfo, gfo, befo), 0.f);
        dst[nt*16] = val;
      }
    }
  }
}

extern "C" void kernel_launch(void* const* d_in, const int* in_sizes, int n_in,
                              void* d_out, int out_size, void* d_ws, size_t ws_size,
                              hipStream_t stream){
  const float* xyz     = (const float*)d_in[0];
  const float* feature = (const float*)d_in[1];
  const float* w0  = (const float*)d_in[2];
  const float* b0  = (const float*)d_in[3];
  const float* g0  = (const float*)d_in[4];
  const float* be0 = (const float*)d_in[5];
  const float* w1  = (const float*)d_in[6];
  const float* b1  = (const float*)d_in[7];
  const float* g1  = (const float*)d_in[8];
  const float* be1 = (const float*)d_in[9];
  const float* w2  = (const float*)d_in[10];
  const float* b2  = (const float*)d_in[11];
  const float* wl  = (const float*)d_in[12];
  const float* bl  = (const float*)d_in[13];
  const float* gl  = (const float*)d_in[14];
  const float* bel = (const float*)d_in[15];
  const float* wf  = (const float*)d_in[16];
  const float* bf  = (const float*)d_in[17];
  const float* gf  = (const float*)d_in[18];
  const float* bef = (const float*)d_in[19];
  float* out = (float*)d_out;

  char* ws = (char*)d_ws;
  unsigned short* featB = (unsigned short*)(ws + 0);          // 16 MB
  float*          part  = (float*)(ws + 16777216);            // 16 MB
  unsigned short* aggB  = (unsigned short*)(ws + 50331648);   // 33.5 MB
  unsigned short* wlB   = (unsigned short*)(ws + 83886080);   // 1 MB
  unsigned short* wfB   = (unsigned short*)(ws + 84934656);   // 48 KB
  float*          nxyz  = (float*)(ws + 84983808);            // 48 KB
  float*          nfT   = (float*)(ws + 85557248);            // 2 MB
  int*            syncw = (int*)  (ws + 87654400);            // 32 ints: flags[16] + tdone[16]
  int*            flags = syncw;
  int*            tdone = syncw + 16;

  k_zero   <<<1,   64, 0, stream>>>(syncw);
  k_pre    <<<256, 256, 0, stream>>>(xyz, nxyz, feature, featB, wl, wlB, wf, wfB,
                                     w0,b0,g0,be0, w1,b1,g1,be1, w2,b2, aggB, flags, tdone);
  k_nf_part<<<512, 256, 0, stream>>>(aggB, wlB, part);
  k_nf_ep  <<<512, 256, 0, stream>>>(part, bl, gl, bel, nfT);
  k_final  <<<BB*(NN/128), 256, 0, stream>>>(xyz, nxyz, nfT, featB, wfB, bf, gf, bef, out);
}

// Round 14
// 558.961 us; speedup vs baseline: 1.7187x; 1.7187x over previous
//
#include <hip/hip_runtime.h>
#include <hip/hip_bf16.h>
#include <cstdint>
#include <cstddef>

#define BB   16
#define NN   8192
#define DD   64
#define MM   256
#define SS   32
#define OUTC 128
#define WCC  64

using short8 = __attribute__((ext_vector_type(8))) short;
using f32x4  = __attribute__((ext_vector_type(4))) float;

__device__ __forceinline__ float bnf(float x, float g, float be){
    const float BNS = 0.99999500003749969f; // 1/sqrt(1+1e-5)
    return g * (x * BNS) + be;
}
__device__ __forceinline__ unsigned short f2bf(float f){
    __hip_bfloat16 h = __float2bfloat16(f);
    return *reinterpret_cast<unsigned short*>(&h);
}
__device__ __forceinline__ float bf2f(unsigned short u){
    return __uint_as_float(((unsigned)u) << 16);
}

// ============ merged prologue: FPS + feature->bf16 transpose + weight casts ============
// blocks 0..15: FPS | 16..2063: feat transpose | 2064..2575: wl cast | 2576..2599: wf cast
#define PRE_GRID (16 + 2048 + 512 + 24)

__global__ __launch_bounds__(256, 1) void k_pre(const float* __restrict__ xyz, float* __restrict__ nxyz,
    const float* __restrict__ feature, unsigned short* __restrict__ featB,
    const float* __restrict__ wl, unsigned short* __restrict__ wlB,
    const float* __restrict__ wf, unsigned short* __restrict__ wfB){
  __shared__ union {
    struct {
      float sxyz[NN*3];
      float snew[MM*3];
      unsigned long long skey[2][4];
    } f;
    float tile[64][65];
  } sm;
  const int t = threadIdx.x;
  int blk = blockIdx.x;

  if (blk < 16){
    // ---- FPS: 256 thr, expansion distance, single u64 DPP chain, 1 barrier/step ----
    const int b = blk;
    const float* xb = xyz + (size_t)b*NN*3;
    for (int i = t; i < NN*3; i += 256) sm.f.sxyz[i] = xb[i];
    float px[32], py[32], pz[32], pn[32], dist[32];
#pragma unroll
    for (int i=0;i<32;i++){
      const int id = i*256 + t;
      px[i] = xb[id*3+0]; py[i] = xb[id*3+1]; pz[i] = xb[id*3+2];
      pn[i] = px[i]*px[i] + py[i]*py[i] + pz[i]*pz[i];
      dist[i] = 1e10f;
    }
    __syncthreads();
    float lx = sm.f.sxyz[0], ly = sm.f.sxyz[1], lz = sm.f.sxyz[2];
    if (t==0){ sm.f.snew[0]=lx; sm.f.snew[1]=ly; sm.f.snew[2]=lz; }
    for (int step=1; step<MM; ++step){
      const float nlx = -2.0f*lx, nly = -2.0f*ly, nlz = -2.0f*lz;
      const float l2s = lx*lx + ly*ly + lz*lz;
      float bv = 0.0f; int bil = 0;
#pragma unroll
      for (int i=0;i<32;i++){
        float c  = pn[i] + l2s;
        float d  = __builtin_fmaf(px[i], nlx, __builtin_fmaf(py[i], nly, __builtin_fmaf(pz[i], nlz, c)));
        float nd = fminf(dist[i], d);
        dist[i] = nd;
        bool gt = nd > bv;
        bv  = gt ? nd : bv;
        bil = gt ? i  : bil;     // inline-const candidate (0..31)
      }
      const int bi = bil*256 + t;
      // single u64 DPP max chain: key = (f32bits << 32) | (8191 - idx); max at lane 63
      unsigned long long key = ((unsigned long long)__float_as_uint(bv) << 32) | (unsigned)(NN-1 - bi);
#define DPP_U64_MAX(CTRL) do { \
        unsigned lo_ = (unsigned)key, hi_ = (unsigned)(key >> 32); \
        unsigned olo_ = (unsigned)__builtin_amdgcn_update_dpp((int)lo_, (int)lo_, (CTRL), 0xF, 0xF, 0); \
        unsigned ohi_ = (unsigned)__builtin_amdgcn_update_dpp((int)hi_, (int)hi_, (CTRL), 0xF, 0xF, 0); \
        unsigned long long ok_ = ((unsigned long long)ohi_ << 32) | olo_; \
        key = ok_ > key ? ok_ : key; \
      } while(0)
      DPP_U64_MAX(0x111);
      DPP_U64_MAX(0x112);
      DPP_U64_MAX(0x114);
      DPP_U64_MAX(0x118);
      DPP_U64_MAX(0x142);
      DPP_U64_MAX(0x143);
#undef DPP_U64_MAX
      {
        unsigned klo = (unsigned)__builtin_amdgcn_readlane((int)(unsigned)key, 63);
        unsigned khi = (unsigned)__builtin_amdgcn_readlane((int)(unsigned)(key >> 32), 63);
        key = ((unsigned long long)khi << 32) | klo;
      }
      const int p = step & 1;
      if ((t & 63) == 0) sm.f.skey[p][t>>6] = key;
      __syncthreads();   // single barrier per step
      unsigned long long k0=sm.f.skey[p][0], k1=sm.f.skey[p][1], k2=sm.f.skey[p][2], k3=sm.f.skey[p][3];
      unsigned long long ka = k0>k1?k0:k1, kb = k2>k3?k2:k3;
      unsigned long long kw = ka>kb?ka:kb;
      const int bid = (NN-1) - (int)(unsigned)(kw & 0xFFFFFFFFull);
      lx = sm.f.sxyz[bid*3+0]; ly = sm.f.sxyz[bid*3+1]; lz = sm.f.sxyz[bid*3+2];
      if (t==0){ sm.f.snew[step*3+0]=lx; sm.f.snew[step*3+1]=ly; sm.f.snew[step*3+2]=lz; }
    }
    __syncthreads();
    for (int i = t; i < MM*3; i += 256) nxyz[(size_t)b*MM*3 + i] = sm.f.snew[i];
    return;
  }
  blk -= 16;
  if (blk < 2048){
    // ---------------- feature transpose (B,D,N) -> featB (B,N,D) bf16 ----------------
    const int b  = blk >> 7;
    const int n0 = (blk & 127) << 6;
    {
      const int d = t >> 2, j0 = (t & 3) << 4;
      const float* src = feature + ((size_t)b*DD + d)*NN + n0 + j0;
#pragma unroll
      for (int i=0;i<16;i+=4){
        float4 v = *(const float4*)(src + i);
        sm.tile[d][j0+i+0]=v.x; sm.tile[d][j0+i+1]=v.y; sm.tile[d][j0+i+2]=v.z; sm.tile[d][j0+i+3]=v.w;
      }
    }
    __syncthreads();
    {
      const int j = t >> 2, d0 = (t & 3) << 4;
      unsigned short hv[16];
#pragma unroll
      for (int i=0;i<16;i++) hv[i] = f2bf(sm.tile[d0+i][j]);
      unsigned short* dst = featB + ((size_t)b*NN + n0 + j)*64 + d0;
      *(uint4*)(dst)     = *(uint4*)(&hv[0]);
      *(uint4*)(dst + 8) = *(uint4*)(&hv[8]);
    }
    return;
  }
  blk -= 2048;
  if (blk < 512){
    int idx = (blk*256 + t)*4;
    float4 v = *(const float4*)(wl + idx);
    ushort4 h = make_ushort4(f2bf(v.x), f2bf(v.y), f2bf(v.z), f2bf(v.w));
    *(ushort4*)(wlB + idx) = h;
    return;
  }
  blk -= 512;
  {
    int idx = (blk*256 + t)*4;
    if (idx < 128*192){
      float4 v = *(const float4*)(wf + idx);
      ushort4 h = make_ushort4(f2bf(v.x), f2bf(v.y), f2bf(v.z), f2bf(v.w));
      *(ushort4*)(wfB + idx) = h;
    }
  }
}

// ---------------- ball query + 3-layer MLP (LDS-staged) ----------------
__global__ __launch_bounds__(64) void k_bq_mlp(const float* __restrict__ xyz,
    const float* __restrict__ nxyz,
    const float* __restrict__ w0, const float* __restrict__ b0,
    const float* __restrict__ g0, const float* __restrict__ be0,
    const float* __restrict__ w1, const float* __restrict__ b1,
    const float* __restrict__ g1, const float* __restrict__ be1,
    const float* __restrict__ w2, const float* __restrict__ b2,
    int* __restrict__ gidx, float* __restrict__ wbuf){
  const int bm = blockIdx.x;
  const int b  = bm >> 8;
  const int c  = threadIdx.x;
  __shared__ int   sidx[SS];
  __shared__ float sgx[3][SS];
  __shared__ float sh0[SS][WCC];
  __shared__ float sh1[SS][WCC];

  const float w0r0 = w0[c*3+0], w0r1 = w0[c*3+1], w0r2 = w0[c*3+2];
  const float b0c=b0[c], g0c=g0[c], be0c=be0[c];
  const float b1c=b1[c], g1c=g1[c], be1c=be1[c], b2c=b2[c];
  float w1r[64], w2r[64];
#pragma unroll
  for (int i=0;i<16;i++){
    float4 v = *(const float4*)(w1 + c*64 + i*4);
    w1r[i*4+0]=v.x; w1r[i*4+1]=v.y; w1r[i*4+2]=v.z; w1r[i*4+3]=v.w;
    float4 u = *(const float4*)(w2 + c*64 + i*4);
    w2r[i*4+0]=u.x; w2r[i*4+1]=u.y; w2r[i*4+2]=u.z; w2r[i*4+3]=u.w;
  }
  const float cx = nxyz[bm*3+0], cy = nxyz[bm*3+1], cz = nxyz[bm*3+2];
  const float* xb = xyz + (size_t)b*NN*3;
  const float R2 = (float)(0.4*0.4);
  int cnt = 0;
  for (int n0=0; n0<NN && cnt<SS; n0+=64){
    int n = n0 + c;
    float dx = xb[n*3+0]-cx, dy = xb[n*3+1]-cy, dz = xb[n*3+2]-cz;
    float d2 = dx*dx+dy*dy+dz*dz;
    bool in = (d2 <= R2);
    unsigned long long mk = __ballot(in);
    int rank = cnt + (int)__popcll(mk & ((1ull<<c)-1ull));
    if (in && rank < SS) sidx[rank] = n;
    cnt += (int)__popcll(mk);
  }
  int total = min(cnt, SS);
  __syncthreads();
  int i0 = sidx[0];
  if (c >= total && c < SS) sidx[c] = i0;
  __syncthreads();
  if (c < SS){
    int p = sidx[c];
    gidx[bm*SS + c] = p;
    sgx[0][c] = xb[p*3+0]-cx;
    sgx[1][c] = xb[p*3+1]-cy;
    sgx[2][c] = xb[p*3+2]-cz;
  }
  __syncthreads();
  for (int s=0;s<SS;s++){
    float pre = w0r0*sgx[0][s] + w0r1*sgx[1][s] + w0r2*sgx[2][s] + b0c;
    sh0[s][c] = fmaxf(bnf(pre, g0c, be0c), 0.f);
  }
  __syncthreads();
  for (int s=0;s<SS;s++){
    float a = b1c;
#pragma unroll
    for (int k=0;k<64;k+=4){
      float4 h = *(const float4*)(&sh0[s][k]);
      a += w1r[k]*h.x + w1r[k+1]*h.y + w1r[k+2]*h.z + w1r[k+3]*h.w;
    }
    sh1[s][c] = fmaxf(bnf(a, g1c, be1c), 0.f);
  }
  __syncthreads();
  float* wb = wbuf + (size_t)bm*SS*WCC;
  for (int s=0;s<SS;s++){
    float a = b2c;
#pragma unroll
    for (int k=0;k<64;k+=4){
      float4 h = *(const float4*)(&sh1[s][k]);
      a += w2r[k]*h.x + w2r[k+1]*h.y + w2r[k+2]*h.z + w2r[k+3]*h.w;
    }
    wb[s*WCC + c] = a;
  }
}

// ---------------- aggregation -> agg in bf16 [4096][4096] ----------------
__global__ __launch_bounds__(256) void k_agg(const unsigned short* __restrict__ featB,
                                             const float* __restrict__ wbuf,
                                             const int* __restrict__ gidx,
                                             unsigned short* __restrict__ aggB){
  const int bm = blockIdx.x;
  const int b  = bm >> 8;
  __shared__ float wt[SS][WCC];
  __shared__ int   sidx[SS];
  const int t = threadIdx.x;
  const float* wsrc = wbuf + (size_t)bm*SS*WCC;
#pragma unroll
  for (int i=0;i<8;i++){
    int li = t + i*256;
    ((float*)wt)[li] = wsrc[li];
  }
  if (t < SS) sidx[t] = gidx[bm*SS + t];
  __syncthreads();
  const int d  = t & 63;
  const int wg = t >> 6;
  float acc[16];
#pragma unroll
  for (int j=0;j<16;j++) acc[j]=0.f;
  const unsigned short* fb = featB + (size_t)b*NN*64;
  for (int s=0;s<SS;s++){
    float fv = bf2f(fb[(size_t)sidx[s]*64 + d]);
#pragma unroll
    for (int j=0;j<16;j++) acc[j] += fv * wt[s][wg*16+j];
  }
  unsigned short h[16];
#pragma unroll
  for (int j=0;j<16;j++) h[j] = f2bf(acc[j]);
  unsigned short* ab = aggB + (size_t)bm*4096 + d*64 + wg*16;
  *(uint4*)(ab)     = *(uint4*)(&h[0]);
  *(uint4*)(ab + 8) = *(uint4*)(&h[8]);
}

// ---------------- new_feature GEMM via MFMA bf16, split-K x8 partials ----------------
__global__ __launch_bounds__(256) void k_nf_part(const unsigned short* __restrict__ aggB,
                                                 const unsigned short* __restrict__ wlB,
                                                 float* __restrict__ part){
  const int blk = blockIdx.x;
  const int rb  = blk >> 3;          // 64 row-blocks (64 rows each)
  const int ks  = blk & 7;           // 8 K-slices of 512
  const int wid = threadIdx.x >> 6, lane = threadIdx.x & 63;
  const int m0 = rb*64 + wid*16;
  const int r  = lane & 15, kg = lane >> 4;
  f32x4 acc[8];
#pragma unroll
  for (int i=0;i<8;i++) acc[i] = (f32x4){0.f,0.f,0.f,0.f};
  const short* arow = (const short*)aggB + (size_t)(m0 + r)*4096 + ks*512 + kg*8;
  const short* brow = (const short*)wlB  + (size_t)r*4096        + ks*512 + kg*8;
#pragma unroll 4
  for (int kc=0; kc<16; kc++){
    short8 a = *(const short8*)(arow + kc*32);
#pragma unroll
    for (int ot=0; ot<8; ot++){
      short8 bfr = *(const short8*)(brow + (size_t)ot*16*4096 + kc*32);
      acc[ot] = __builtin_amdgcn_mfma_f32_16x16x32_bf16(a, bfr, acc[ot], 0, 0, 0);
    }
  }
  float* pb = part + ((size_t)ks << 19);   // 4096*128 floats per slice
#pragma unroll
  for (int ot=0; ot<8; ot++){
#pragma unroll
    for (int rr=0; rr<4; rr++){
      int row = m0 + kg*4 + rr;
      pb[(size_t)row*128 + ot*16 + r] = acc[ot][rr];
    }
  }
}

// ---------------- nf epilogue: sum 8 partials + bias + bn + relu ----------------
__global__ __launch_bounds__(256) void k_nf_ep(const float* __restrict__ part,
    const float* __restrict__ bl, const float* __restrict__ gl, const float* __restrict__ bel,
    float* __restrict__ nfT){
  const int gid = blockIdx.x*256 + threadIdx.x;
  const int base = gid*4;
  const int o0 = base & 127;
  float sum[4] = {0.f, 0.f, 0.f, 0.f};
#pragma unroll
  for (int s=0;s<8;s++){
    float4 v = *(const float4*)(part + ((size_t)s<<19) + base);
    sum[0]+=v.x; sum[1]+=v.y; sum[2]+=v.z; sum[3]+=v.w;
  }
  float ov[4];
#pragma unroll
  for (int j=0;j<4;j++){
    const int o = o0 + j;
    ov[j] = fmaxf(bnf(sum[j] + bl[o], gl[o], bel[o]), 0.f);
  }
  *(float4*)(nfT + base) = make_float4(ov[0],ov[1],ov[2],ov[3]);
}

// ---------------- fused: 3-NN interp + final conv via MFMA bf16 ----------------
__global__ __launch_bounds__(256) void k_final(const float* __restrict__ xyz,
    const float* __restrict__ nxyz, const float* __restrict__ nfT,
    const unsigned short* __restrict__ featB, const unsigned short* __restrict__ wfB,
    const float* __restrict__ bf, const float* __restrict__ gf, const float* __restrict__ bef,
    float* __restrict__ out){
  const int blk = blockIdx.x;
  const int b  = blk >> 6;
  const int n0 = (blk & 63) << 7;
  __shared__ float snew[MM*3];
  __shared__ float sw[128][3];
  __shared__ int   si[128][3];
  const int t = threadIdx.x;
  if (t < 192){
    float4 v = *(const float4*)(nxyz + (size_t)b*MM*3 + t*4);
    snew[t*4+0]=v.x; snew[t*4+1]=v.y; snew[t*4+2]=v.z; snew[t*4+3]=v.w;
  }
  __syncthreads();
  if (t < 128){
    const int n = n0 + t;
    const float x = xyz[((size_t)b*NN+n)*3+0];
    const float y = xyz[((size_t)b*NN+n)*3+1];
    const float z = xyz[((size_t)b*NN+n)*3+2];
    float d1=1e30f, d2=1e30f, d3=1e30f; int i1=0,i2=0,i3=0;
    for (int m=0;m<MM;m++){
      float dx=x-snew[m*3+0], dy=y-snew[m*3+1], dz=z-snew[m*3+2];
      float d = dx*dx+dy*dy+dz*dz;
      if (d < d3){
        if (d < d1){ d3=d2;i3=i2; d2=d1;i2=i1; d1=d;i1=m; }
        else if (d < d2){ d3=d2;i3=i2; d2=d;i2=m; }
        else { d3=d;i3=m; }
      }
    }
    float r1=1.f/(d1+1e-8f), r2=1.f/(d2+1e-8f), r3=1.f/(d3+1e-8f);
    float rs = 1.f/(r1+r2+r3);
    sw[t][0]=r1*rs; sw[t][1]=r2*rs; sw[t][2]=r3*rs;
    si[t][0]=i1; si[t][1]=i2; si[t][2]=i3;
  }
  __syncthreads();

  const int w = t >> 6, lane = t & 63;
  const int r = lane & 15, kg = lane >> 4;
  float wA[8][3]; int iA[8][3];
#pragma unroll
  for (int nt=0;nt<8;nt++){
    int n = nt*16 + r;
    wA[nt][0]=sw[n][0]; wA[nt][1]=sw[n][1]; wA[nt][2]=sw[n][2];
    iA[nt][0]=si[n][0]*128; iA[nt][1]=si[n][1]*128; iA[nt][2]=si[n][2]*128;
  }
  const float* nfb = nfT + (size_t)b*MM*128;
  const unsigned short* fbB = featB + ((size_t)b*NN + n0)*64;
  const unsigned short* wfRow0 = wfB + (size_t)(w*32 +      r)*192 + kg*8;
  const unsigned short* wfRow1 = wfB + (size_t)(w*32 + 16 + r)*192 + kg*8;
  f32x4 acc[2][8];
#pragma unroll
  for (int i=0;i<2;i++)
#pragma unroll
    for (int j=0;j<8;j++) acc[i][j] = (f32x4){0.f,0.f,0.f,0.f};

#pragma unroll
  for (int c=0;c<6;c++){
    short8 a0 = *(const short8*)(wfRow0 + c*32);
    short8 a1 = *(const short8*)(wfRow1 + c*32);
    if (c < 4){
      const int k8 = c*32 + kg*8;
#pragma unroll
      for (int nt=0;nt<8;nt++){
        const float* p0 = nfb + iA[nt][0] + k8;
        const float* p1 = nfb + iA[nt][1] + k8;
        const float* p2 = nfb + iA[nt][2] + k8;
        float4 xa = *(const float4*)(p0), xb4 = *(const float4*)(p0+4);
        float4 ya = *(const float4*)(p1), yb4 = *(const float4*)(p1+4);
        float4 za = *(const float4*)(p2), zb4 = *(const float4*)(p2+4);
        const float w0v=wA[nt][0], w1v=wA[nt][1], w2v=wA[nt][2];
        float e0 = w0v*xa.x + w1v*ya.x + w2v*za.x;
        float e1 = w0v*xa.y + w1v*ya.y + w2v*za.y;
        float e2 = w0v*xa.z + w1v*ya.z + w2v*za.z;
        float e3 = w0v*xa.w + w1v*ya.w + w2v*za.w;
        float e4 = w0v*xb4.x + w1v*yb4.x + w2v*zb4.x;
        float e5 = w0v*xb4.y + w1v*yb4.y + w2v*zb4.y;
        float e6 = w0v*xb4.z + w1v*yb4.z + w2v*zb4.z;
        float e7 = w0v*xb4.w + w1v*yb4.w + w2v*zb4.w;
        short8 bfr = { (short)f2bf(e0), (short)f2bf(e1), (short)f2bf(e2), (short)f2bf(e3),
                       (short)f2bf(e4), (short)f2bf(e5), (short)f2bf(e6), (short)f2bf(e7) };
        acc[0][nt] = __builtin_amdgcn_mfma_f32_16x16x32_bf16(a0, bfr, acc[0][nt], 0, 0, 0);
        acc[1][nt] = __builtin_amdgcn_mfma_f32_16x16x32_bf16(a1, bfr, acc[1][nt], 0, 0, 0);
      }
    } else {
      const int d8 = (c-4)*32 + kg*8;
#pragma unroll
      for (int nt=0;nt<8;nt++){
        short8 bfr = *(const short8*)(fbB + (size_t)(nt*16 + r)*64 + d8);
        acc[0][nt] = __builtin_amdgcn_mfma_f32_16x16x32_bf16(a0, bfr, acc[0][nt], 0, 0, 0);
        acc[1][nt] = __builtin_amdgcn_mfma_f32_16x16x32_bf16(a1, bfr, acc[1][nt], 0, 0, 0);
      }
    }
  }
#pragma unroll
  for (int ot=0; ot<2; ot++){
#pragma unroll
    for (int rr=0; rr<4; rr++){
      const int o = w*32 + ot*16 + kg*4 + rr;
      const float bfo = bf[o], gfo = gf[o], befo = bef[o];
      float* dst = out + ((size_t)b*OUTC + o)*NN + n0 + r;
#pragma unroll
      for (int nt=0;nt<8;nt++){
        float val = fmaxf(bnf(acc[ot][nt][rr] + bfo, gfo, befo), 0.f);
        dst[nt*16] = val;
      }
    }
  }
}

extern "C" void kernel_launch(void* const* d_in, const int* in_sizes, int n_in,
                              void* d_out, int out_size, void* d_ws, size_t ws_size,
                              hipStream_t stream){
  const float* xyz     = (const float*)d_in[0];
  const float* feature = (const float*)d_in[1];
  const float* w0  = (const float*)d_in[2];
  const float* b0  = (const float*)d_in[3];
  const float* g0  = (const float*)d_in[4];
  const float* be0 = (const float*)d_in[5];
  const float* w1  = (const float*)d_in[6];
  const float* b1  = (const float*)d_in[7];
  const float* g1  = (const float*)d_in[8];
  const float* be1 = (const float*)d_in[9];
  const float* w2  = (const float*)d_in[10];
  const float* b2  = (const float*)d_in[11];
  const float* wl  = (const float*)d_in[12];
  const float* bl  = (const float*)d_in[13];
  const float* gl  = (const float*)d_in[14];
  const float* bel = (const float*)d_in[15];
  const float* wf  = (const float*)d_in[16];
  const float* bf  = (const float*)d_in[17];
  const float* gf  = (const float*)d_in[18];
  const float* bef = (const float*)d_in[19];
  float* out = (float*)d_out;

  char* ws = (char*)d_ws;
  unsigned short* featB = (unsigned short*)(ws + 0);          // 16 MB
  float*          wbuf  = (float*)(ws + 16777216);            // 33.5 MB (dead after k_agg)
  float*          part  = (float*)(ws + 16777216);            // 16 MB, reuses wbuf region
  unsigned short* aggB  = (unsigned short*)(ws + 50331648);   // 33.5 MB
  unsigned short* wlB   = (unsigned short*)(ws + 83886080);   // 1 MB
  unsigned short* wfB   = (unsigned short*)(ws + 84934656);   // 48 KB
  float*          nxyz  = (float*)(ws + 84983808);            // 48 KB
  int*            gidx  = (int*)  (ws + 85032960);            // 512 KB
  float*          nfT   = (float*)(ws + 85557248);            // 2 MB

  k_pre    <<<PRE_GRID, 256, 0, stream>>>(xyz, nxyz, feature, featB, wl, wlB, wf, wfB);
  k_bq_mlp <<<BB*MM, 64, 0, stream>>>(xyz, nxyz, w0,b0,g0,be0, w1,b1,g1,be1, w2,b2, gidx, wbuf);
  k_agg    <<<BB*MM, 256, 0, stream>>>(featB, wbuf, gidx, aggB);
  k_nf_part<<<512,  256, 0, stream>>>(aggB, wlB, part);
  k_nf_ep  <<<512,  256, 0, stream>>>(part, bl, gl, bel, nfT);
  k_final  <<<BB*(NN/128), 256, 0, stream>>>(xyz, nxyz, nfT, featB, wfB, bf, gf, bef, out);
}